// Round 3
// baseline (148.925 us; speedup 1.0000x reference)
//
#include <hip/hip_runtime.h>
#include <hip/hip_fp16.h>

// MCLoss: mean |lap(gt) - lap(pr)| == mean |lap(gt - pr)|  (laplacian is linear).
// B=16, N=100000, M=9, nb[:,0]==i by construction.
//
// k1: tiled transpose+diff, dwordx4-vectorized both sides:
//     d[i][b] = half4(gt[b,i]-pr[b,i], 0), layout (N+1,16) of 8B -> gather row=128B.
//     Row N zeroed (absorbs idx==N); acc & done-counter zeroed.
// k2: 4 i's x 1 b per thread -> 32 independent 8B gathers in flight (latency-bound
//     kernel: rate = outstanding/latency). nb rows for 4 consecutive i = 36
//     consecutive ints = 9 aligned uint4 loads. Last block writes d_out (fused k3).

#define NT 256
#define TI 64   // i's per k1 block (multiple of 4)

union H4 {
  uint2 u;
  __half2 h[2];  // h[0]=(x,y) h[1]=(z,pad)
};

__device__ __forceinline__ void unpack(uint2 v, float& x, float& y, float& z) {
  H4 c; c.u = v;
  float2 xy = __half22float2(c.h[0]);
  x = xy.x; y = xy.y;
  z = __half2float(__low2half(c.h[1]));
}

__global__ __launch_bounds__(NT) void k1_diff_pack(
    const float* __restrict__ gt, const float* __restrict__ pr,
    uint2* __restrict__ d, float* __restrict__ acc,
    unsigned* __restrict__ cnt, int N) {
  __shared__ float sm[16][3 * TI + 4];   // row=196 floats: 16B-aligned rows, 2-way-max banks
  const int t = threadIdx.x;
  const int i0 = blockIdx.x * TI;
  const int ni = min(TI, N - i0);        // multiple of 4 (N%4==0, TI%4==0)
  const int nq = (3 * ni) >> 2;          // valid float4s per segment (<=48)

  // Phase 1: 16 segments x 48 float4 (contiguous, aligned) -> LDS
#pragma unroll
  for (int k = 0; k < 3; k++) {          // 768 float4 / 256 threads
    int flat = t + k * NT;
    int seg = flat / 48;
    int q = flat - seg * 48;
    if (q < nq) {
      const float4* ga = (const float4*)(gt + ((size_t)seg * N + i0) * 3);
      const float4* pa = (const float4*)(pr + ((size_t)seg * N + i0) * 3);
      float4 a = ga[q];
      float4 p = pa[q];
      float4 df = make_float4(a.x - p.x, a.y - p.y, a.z - p.z, a.w - p.w);
      *(float4*)&sm[seg][q * 4] = df;
    }
  }
  __syncthreads();

  // Phase 2: coalesced 8B writes in transposed (i,b) order.
#pragma unroll
  for (int k = 0; k < (16 * TI) / NT; k++) {   // 4 iters
    int el = t + k * NT;
    int il = el >> 4;
    int b = el & 15;
    if (il < ni) {
      float x = sm[b][il * 3 + 0];
      float y = sm[b][il * 3 + 1];
      float z = sm[b][il * 3 + 2];
      H4 o;
      o.h[0] = __floats2half2_rn(x, y);
      o.h[1] = __floats2half2_rn(z, 0.0f);
      d[(size_t)(i0 + il) * 16 + b] = o.u;
    }
  }

  if (blockIdx.x == 0) {
    if (t < 16) { uint2 z; z.x = 0u; z.y = 0u; d[(size_t)N * 16 + t] = z; }
    if (t == 16) *acc = 0.0f;
    if (t == 17) *cnt = 0u;
  }
}

__global__ __launch_bounds__(NT) void k2_lap_loss(
    const uint2* __restrict__ dp, const int* __restrict__ nb,
    const float* __restrict__ nn, float* __restrict__ acc,
    unsigned* __restrict__ cnt, float* __restrict__ out,
    float scale, int N, int nblocks) {
  const int f = blockIdx.x * NT + threadIdx.x;
  const int g = f >> 4;          // group of 4 consecutive i's
  const int b = f & 15;
  const int i0 = g * 4;
  float s = 0.0f;

  if (i0 + 3 < N) {
    // nb rows for i0..i0+3: ints [36g .. 36g+35], 16B-aligned (144g bytes).
    const uint4* nbr = (const uint4*)(nb + (size_t)g * 36);
    uint4 r[9];
#pragma unroll
    for (int k = 0; k < 9; k++) r[k] = nbr[k];
    float4 w4 = *(const float4*)(nn + i0);

    uint2 c[4];
#pragma unroll
    for (int q = 0; q < 4; q++) c[q] = dp[(size_t)(i0 + q) * 16 + b];

    const unsigned* rf = (const unsigned*)r;   // 36 ints; row q = rf[9q+1 .. 9q+8]
    int id[32];
#pragma unroll
    for (int q = 0; q < 4; q++)
#pragma unroll
      for (int j = 0; j < 8; j++) id[q * 8 + j] = (int)rf[9 * q + 1 + j];

    // 32 independent gathers in flight
    uint2 v[32];
#pragma unroll
    for (int m = 0; m < 32; m++) v[m] = dp[(size_t)id[m] * 16 + b];

    const float w[4] = {w4.x, w4.y, w4.z, w4.w};
#pragma unroll
    for (int q = 0; q < 4; q++) {
      float ax, ay, az;
      unpack(c[q], ax, ay, az);
      ax *= w[q]; ay *= w[q]; az *= w[q];
#pragma unroll
      for (int j = 0; j < 8; j++) {
        float x, y, z;
        unpack(v[q * 8 + j], x, y, z);
        ax -= x; ay -= y; az -= z;
      }
      s += fabsf(ax) + fabsf(ay) + fabsf(az);
    }
  } else if (i0 < N) {
    for (int q = 0; q < 4; q++) {
      int i = i0 + q;
      if (i >= N) break;
      float wq = nn[i];
      float ax, ay, az;
      unpack(dp[(size_t)i * 16 + b], ax, ay, az);
      ax *= wq; ay *= wq; az *= wq;
      for (int j = 1; j < 9; j++) {
        int idx = nb[(size_t)i * 9 + j];
        float x, y, z;
        unpack(dp[(size_t)idx * 16 + b], x, y, z);
        ax -= x; ay -= y; az -= z;
      }
      s += fabsf(ax) + fabsf(ay) + fabsf(az);
    }
  }

  // wave (64) -> block -> one atomic
#pragma unroll
  for (int off = 32; off > 0; off >>= 1) s += __shfl_down(s, off);
  __shared__ float sm[NT / 64];
  int lane = threadIdx.x & 63, wv = threadIdx.x >> 6;
  if (lane == 0) sm[wv] = s;
  __syncthreads();
  if (threadIdx.x == 0) {
    float tt = 0.0f;
#pragma unroll
    for (int k = 0; k < NT / 64; k++) tt += sm[k];
    atomicAdd(acc, tt);
    __threadfence();                          // make acc-add visible device-wide
    unsigned done = atomicAdd(cnt, 1u);
    if (done == (unsigned)(nblocks - 1)) {    // fused k3: last block finishes
      float total = atomicAdd(acc, 0.0f);     // coherent read-back
      out[0] = total * scale;
    }
  }
}

// ---------- fallback path (ws too small, K!=8, or N%4!=0) ----------
__global__ void k0_zero(float* __restrict__ acc) {
  if (threadIdx.x == 0) *acc = 0.0f;
}

__global__ __launch_bounds__(NT) void k2_direct(
    const float* __restrict__ gt, const float* __restrict__ pr,
    const int* __restrict__ nb, const float* __restrict__ nn,
    float* __restrict__ acc, int N, int K) {
  int u = blockIdx.x * NT + threadIdx.x;
  float s = 0.0f;
  if (u < 16 * N) {
    int b = u / N;
    int i = u - b * N;
    size_t cidx = ((size_t)b * N + i) * 3;
    float w = nn[i];
    float ax = (gt[cidx] - pr[cidx]) * w;
    float ay = (gt[cidx + 1] - pr[cidx + 1]) * w;
    float az = (gt[cidx + 2] - pr[cidx + 2]) * w;
    const int* row = nb + (size_t)i * (K + 1) + 1;
    for (int j = 0; j < K; j++) {
      int idx = row[j];
      if (idx < N) {
        size_t p = ((size_t)b * N + idx) * 3;
        ax -= (gt[p] - pr[p]);
        ay -= (gt[p + 1] - pr[p + 1]);
        az -= (gt[p + 2] - pr[p + 2]);
      }
    }
    s = fabsf(ax) + fabsf(ay) + fabsf(az);
  }
#pragma unroll
  for (int off = 32; off > 0; off >>= 1) s += __shfl_down(s, off);
  __shared__ float sm[NT / 64];
  int lane = threadIdx.x & 63, wv = threadIdx.x >> 6;
  if (lane == 0) sm[wv] = s;
  __syncthreads();
  if (threadIdx.x == 0) {
    float tt = 0.0f;
#pragma unroll
    for (int k = 0; k < NT / 64; k++) tt += sm[k];
    atomicAdd(acc, tt);
  }
}

__global__ void k3_finalize(const float* __restrict__ acc,
                            float* __restrict__ out, float scale) {
  if (threadIdx.x == 0) out[0] = acc[0] * scale;
}

extern "C" void kernel_launch(void* const* d_in, const int* in_sizes, int n_in,
                              void* d_out, int out_size, void* d_ws, size_t ws_size,
                              hipStream_t stream) {
  const float* gt = (const float*)d_in[0];
  const float* pr = (const float*)d_in[1];
  const int*   nb = (const int*)d_in[2];
  const float* nn = (const float*)d_in[3];
  int N = in_sizes[3];           // 100000
  int M = in_sizes[2] / N;       // 9
  int K = M - 1;                 // 8

  float scale = 1.0f / (16.0f * (float)N * 3.0f);
  size_t dbytes = (size_t)(N + 1) * 16 * sizeof(uint2);
  size_t need = dbytes + 64;

  if (K == 8 && (N & 3) == 0 && ws_size >= need) {
    uint2*    d   = (uint2*)d_ws;
    float*    acc = (float*)((char*)d_ws + dbytes);
    unsigned* cnt = (unsigned*)(acc + 1);

    int b1 = (N + TI - 1) / TI;
    k1_diff_pack<<<b1, NT, 0, stream>>>(gt, pr, d, acc, cnt, N);

    int groups = (N + 3) / 4;
    int b2 = ((size_t)groups * 16 + NT - 1) / NT;
    k2_lap_loss<<<b2, NT, 0, stream>>>(d, nb, nn, acc, cnt, (float*)d_out,
                                       scale, N, b2);
  } else {
    float* acc = (float*)d_ws;
    k0_zero<<<1, 64, 0, stream>>>(acc);
    int b2 = (16 * N + NT - 1) / NT;
    k2_direct<<<b2, NT, 0, stream>>>(gt, pr, nb, nn, acc, N, K);
    k3_finalize<<<1, 64, 0, stream>>>(acc, (float*)d_out, scale);
  }
}